// Round 9
// baseline (389.693 us; speedup 1.0000x reference)
//
#include <hip/hip_runtime.h>

// VQ nearest-embedding. R9: barrier-free MFMA K-loop.
// argmin_k ||x-e_k||^2 == argmin_k (0.5*||e_k||^2 - x.e_k).
// x = xh+xl, e = eh+el (fp16 RNE); 3 MFMA terms (hh, hl, lh) - validated R5-R8.
// A (x panel, 64 lat x 256 d) staged ONCE in LDS (XOR-swizzled, conflict-free);
// B fragments loaded straight from pre-split e16 (global, L2-resident) into
// registers, double-buffered -> the 128-step inner loop has NO barriers and
// NO LDS writes. Block covers all 2048 codes -> final code u32 in row 0 of
// its own batch window (no cross-block combine). ws_size proven < 270 KB (R2),
// so e16 lives in donated d_out rows 4..19 (R7/R8-proven safe).

typedef __attribute__((ext_vector_type(8))) _Float16 half8v;  // 8 fp16 = 4 VGPRs
typedef __attribute__((ext_vector_type(16))) float floatx16;  // 32x32 acc
typedef unsigned int uint;
typedef unsigned short ushort;
typedef unsigned long long ull;

#define DD 256
#define KK 2048
#define SS 1024
#define NN 32768
#define WIN 524288  // ushorts per batch window of d_out (1 MB)
#define MFMA_F16 __builtin_amdgcn_mfma_f32_32x32x16_f16

union HU { _Float16 f; ushort u; };

__device__ __forceinline__ void split16(float v, ushort& h, ushort& l) {
    HU a, b;
    a.f = (_Float16)v;                       // RNE
    b.f = (_Float16)(v - (float)a.f);
    h = a.u; l = b.u;
}

// Fused: split emb -> fp16 hi/lo planes (donated d_out rows 4..19 of each
// batch window) + hn[k] = 0.5*||e_k||^2.  (verbatim from R8 - validated)
__global__ __launch_bounds__(256) void prep_e(const float* __restrict__ emb,
                                              ushort* __restrict__ e16,
                                              float* __restrict__ hn) {
    const uint k = blockIdx.x * 256 + threadIdx.x;   // 2048 threads
    const uint areaH = (k >> 7) * WIN + 8192u + (k & 127u) * 256u;
    const uint areaL = areaH + 16u * WIN;
    float a = 0.f;
#pragma unroll 4
    for (int dg = 0; dg < 32; ++dg) {
        ushort h[8], l[8];
#pragma unroll
        for (int i = 0; i < 8; ++i) {
            float v = emb[(size_t)(dg * 8 + i) * KK + k];
            a += v * v;
            split16(v, h[i], l[i]);
        }
        uint4 t;
        t.x = (uint)h[0] | ((uint)h[1] << 16);
        t.y = (uint)h[2] | ((uint)h[3] << 16);
        t.z = (uint)h[4] | ((uint)h[5] << 16);
        t.w = (uint)h[6] | ((uint)h[7] << 16);
        *reinterpret_cast<uint4*>(&e16[areaH + dg * 8]) = t;
        t.x = (uint)l[0] | ((uint)l[1] << 16);
        t.y = (uint)l[2] | ((uint)l[3] << 16);
        t.z = (uint)l[4] | ((uint)l[5] << 16);
        t.w = (uint)l[6] | ((uint)l[7] << 16);
        *reinterpret_cast<uint4*>(&e16[areaL + dg * 8]) = t;
    }
    hn[k] = 0.5f * a;
}

__global__ __launch_bounds__(256, 2) void vq_fused(
        const float* __restrict__ x, const ushort* __restrict__ e16,
        const float* __restrict__ hn, float* __restrict__ out) {
    // A panel: [plane][lat][256 d], 16-B chunks XOR-swizzled by (lat&7): 64 KB
    __shared__ __align__(16) ushort Ap[2 * 64 * 256];
    __shared__ float sv[4][64];
    __shared__ int   sc[4][64];

    const int tid = threadIdx.x;
    const int lane = tid & 63;
    const int wid = tid >> 6;            // 4 waves, 512 codes each
    const int colk = lane & 31;
    const int half = lane >> 5;
    const int l7 = colk & 7;             // == (32+colk)&7

    const int blk = blockIdx.x;          // 512 blocks x 64 latents
    const int bq = blk >> 4;             // batch
    const int sb = (blk & 15) * 64;      // spatial base

    // ---- stage A panel once: 64 lat x 256 d -> fp16 hi/lo, swizzled ----
    {
        const int lat = tid & 63;
        const int jc0 = tid >> 6;        // wave id -> chunk phase
        const int w7 = lat & 7;
        const float* xp = x + (size_t)bq * DD * SS + sb + lat;
        ushort* aH = Ap + lat * 256;
        ushort* aL = Ap + 64 * 256 + lat * 256;
#pragma unroll
        for (int r = 0; r < 8; ++r) {
            const int jc = jc0 + r * 4;  // chunk index 0..31 (d = 8*jc..+7)
            ushort h[8], l[8];
#pragma unroll
            for (int i = 0; i < 8; ++i) {
                float v = xp[(size_t)(jc * 8 + i) * SS];
                split16(v, h[i], l[i]);
            }
            const int sw = (jc ^ w7) * 8;
            uint4 t;
            t.x = (uint)h[0] | ((uint)h[1] << 16);
            t.y = (uint)h[2] | ((uint)h[3] << 16);
            t.z = (uint)h[4] | ((uint)h[5] << 16);
            t.w = (uint)h[6] | ((uint)h[7] << 16);
            *reinterpret_cast<uint4*>(&aH[sw]) = t;
            t.x = (uint)l[0] | ((uint)l[1] << 16);
            t.y = (uint)l[2] | ((uint)l[3] << 16);
            t.z = (uint)l[4] | ((uint)l[5] << 16);
            t.w = (uint)l[6] | ((uint)l[7] << 16);
            *reinterpret_cast<uint4*>(&aL[sw]) = t;
        }
    }
    __syncthreads();   // barrier #1 (the only one before the reduction)

    const int aB0 = colk * 256;          // m-tile 0 lat row
    const int aB1 = (32 + colk) * 256;   // m-tile 1

    float bestv[2][16];
    int bestc[2][16];
#pragma unroll
    for (int t = 0; t < 2; ++t)
#pragma unroll
        for (int r = 0; r < 16; ++r) { bestv[t][r] = 3.4e38f; bestc[t][r] = 0; }

    const uint wbase = wid * 512;        // this wave's code range

    for (int nt = 0; nt < 8; ++nt) {
        const uint cb = wbase + nt * 64;
        const uint c0 = cb + colk;
        const uint c1 = c0 + 32;
        const ushort* bp0h = e16 + (c0 >> 7) * WIN + 8192u + (c0 & 127u) * 256u + half * 8u;
        const ushort* bp1h = e16 + (c1 >> 7) * WIN + 8192u + (c1 & 127u) * 256u + half * 8u;
        const ushort* bp0l = bp0h + 16u * WIN;
        const ushort* bp1l = bp1h + 16u * WIN;

        floatx16 acc[2][2];
#pragma unroll
        for (int i = 0; i < 2; ++i)
#pragma unroll
            for (int j = 0; j < 2; ++j) acc[i][j] = (floatx16)(0.0f);

        half8v b0h[2], b1h[2], b0l[2], b1l[2];
        b0h[0] = *reinterpret_cast<const half8v*>(bp0h);
        b1h[0] = *reinterpret_cast<const half8v*>(bp1h);
        b0l[0] = *reinterpret_cast<const half8v*>(bp0l);
        b1l[0] = *reinterpret_cast<const half8v*>(bp1l);

#pragma unroll
        for (int ks = 0; ks < 16; ++ks) {
            const int cur = ks & 1, nx = cur ^ 1;
            if (ks < 15) {   // prefetch next k-step's B frags (no barrier!)
                b0h[nx] = *reinterpret_cast<const half8v*>(bp0h + 16 * (ks + 1));
                b1h[nx] = *reinterpret_cast<const half8v*>(bp1h + 16 * (ks + 1));
                b0l[nx] = *reinterpret_cast<const half8v*>(bp0l + 16 * (ks + 1));
                b1l[nx] = *reinterpret_cast<const half8v*>(bp1l + 16 * (ks + 1));
            }
            const int sw = ((2 * ks + half) ^ l7) * 8;
            half8v ah0 = *reinterpret_cast<const half8v*>(&Ap[aB0 + sw]);
            half8v ah1 = *reinterpret_cast<const half8v*>(&Ap[aB1 + sw]);
            half8v al0 = *reinterpret_cast<const half8v*>(&Ap[16384 + aB0 + sw]);
            half8v al1 = *reinterpret_cast<const half8v*>(&Ap[16384 + aB1 + sw]);

            acc[0][0] = MFMA_F16(ah0, b0h[cur], acc[0][0], 0, 0, 0);
            acc[0][0] = MFMA_F16(ah0, b0l[cur], acc[0][0], 0, 0, 0);
            acc[0][0] = MFMA_F16(al0, b0h[cur], acc[0][0], 0, 0, 0);

            acc[0][1] = MFMA_F16(ah0, b1h[cur], acc[0][1], 0, 0, 0);
            acc[0][1] = MFMA_F16(ah0, b1l[cur], acc[0][1], 0, 0, 0);
            acc[0][1] = MFMA_F16(al0, b1h[cur], acc[0][1], 0, 0, 0);

            acc[1][0] = MFMA_F16(ah1, b0h[cur], acc[1][0], 0, 0, 0);
            acc[1][0] = MFMA_F16(ah1, b0l[cur], acc[1][0], 0, 0, 0);
            acc[1][0] = MFMA_F16(al1, b0h[cur], acc[1][0], 0, 0, 0);

            acc[1][1] = MFMA_F16(ah1, b1h[cur], acc[1][1], 0, 0, 0);
            acc[1][1] = MFMA_F16(ah1, b1l[cur], acc[1][1], 0, 0, 0);
            acc[1][1] = MFMA_F16(al1, b1h[cur], acc[1][1], 0, 0, 0);
        }

        // ---- n-tile epilogue: scores -> running per-lane argmin ----
        const float h0 = hn[c0];
        const float h1 = hn[c1];
#pragma unroll
        for (int tm = 0; tm < 2; ++tm) {
#pragma unroll
            for (int r = 0; r < 16; ++r) {
                float s0 = h0 - acc[tm][0][r];
                float s1 = h1 - acc[tm][1][r];
                float v = s0; int cd = (int)c0;
                if (s1 < s0) { v = s1; cd = (int)c1; }   // strict <: smaller code wins
                if (v < bestv[tm][r]) { bestv[tm][r] = v; bestc[tm][r] = cd; }
            }
        }
    }

    // ---- cross-lane argmin over the 32 colk lanes ----
#pragma unroll
    for (int tm = 0; tm < 2; ++tm) {
#pragma unroll
        for (int r = 0; r < 16; ++r) {
            float v = bestv[tm][r];
            int cd = bestc[tm][r];
#pragma unroll
            for (int mk = 1; mk < 32; mk <<= 1) {
                float ov = __shfl_xor(v, mk);
                int oc = __shfl_xor(cd, mk);
                if (ov < v || (ov == v && oc < cd)) { v = ov; cd = oc; }
            }
            if (colk == 0) {
                const int row = (r & 3) + 8 * (r >> 2) + 4 * half;  // verified C/D map
                sv[wid][tm * 32 + row] = v;
                sc[wid][tm * 32 + row] = cd;
            }
        }
    }
    __syncthreads();   // barrier #2
    // ---- combine 4 waves (code ranges ascending -> ties keep smaller) ----
    if (tid < 64) {
        float v = sv[0][tid]; int cd = sc[0][tid];
#pragma unroll
        for (int g = 1; g < 4; ++g) {
            float ov = sv[g][tid]; int oc = sc[g][tid];
            if (ov < v || (ov == v && oc < cd)) { v = ov; cd = oc; }
        }
        // final code -> row 0 of own batch window, own columns (race-free)
        uint* cp = reinterpret_cast<uint*>(out + (size_t)bq * DD * SS);
        cp[sb + tid] = (uint)cd;
    }
}

__global__ __launch_bounds__(256) void gather_kernel(
        const float* __restrict__ emb, float* __restrict__ out) {
    __shared__ int bc[128];
    const int tid = threadIdx.x;
    const int base_n = blockIdx.x * 128;
    const int bq = base_n >> 10;
    const int sb = base_n & (SS - 1);
    if (tid < 128) {   // read OWN columns' codes from row 0 before overwriting
        const uint* cp = reinterpret_cast<const uint*>(out + (size_t)bq * DD * SS);
        bc[tid] = (int)cp[sb + tid];
    }
    __syncthreads();
    const int mq = tid & 31;     // float4 group along m
    const int dg = tid >> 5;     // 0..7, 32 d's each
    const int k0 = bc[mq * 4 + 0];
    const int k1 = bc[mq * 4 + 1];
    const int k2 = bc[mq * 4 + 2];
    const int k3 = bc[mq * 4 + 3];
#pragma unroll 4
    for (int dd = 0; dd < 32; ++dd) {
        const int d = dg * 32 + dd;
        const float* er = emb + (size_t)d * KK;
        float4 o = make_float4(er[k0], er[k1], er[k2], er[k3]);
        reinterpret_cast<float4*>(&out[((size_t)bq * DD + d) * SS + sb])[mq] = o;
    }
}

extern "C" void kernel_launch(void* const* d_in, const int* in_sizes, int n_in,
                              void* d_out, int out_size, void* d_ws, size_t ws_size,
                              hipStream_t stream) {
    const float* x = (const float*)d_in[0];     // (32,256,32,32)
    const float* emb = (const float*)d_in[1];   // (256,2048)
    float* out = (float*)d_out;
    float* hn = (float*)d_ws;                   // 8 KB (proven safe)

    hipLaunchKernelGGL(prep_e, dim3(KK / 256), dim3(256), 0, stream,
                       emb, (ushort*)d_out, hn);
    hipLaunchKernelGGL(vq_fused, dim3(NN / 64), dim3(256), 0, stream,
                       x, (const ushort*)d_out, hn, out);
    hipLaunchKernelGGL(gather_kernel, dim3(NN / 128), dim3(256), 0, stream,
                       emb, out);
}

// Round 10
// 315.004 us; speedup vs baseline: 1.2371x; 1.2371x over previous
//
#include <hip/hip_runtime.h>

// VQ nearest-embedding. R10: barrier-free K-loop + blocked-coalesced B.
// argmin_k ||x-e_k||^2 == argmin_k (0.5*||e_k||^2 - x.e_k).
// x = xh+xl, e = eh+el (fp16 RNE); 3 MFMA terms (hh, hl, lh) - validated R5-R9.
// A (64 lat x 256 d) in LDS once (R9-validated swizzle). B pre-split into
// 1-KB fragment blocks [g][s][p] (code c, half h at byte c*32+h*16) so each
// per-step B load is one CONTIGUOUS 1 KB per wave (fixes R9's 512-B-stride
// scatter -> 4x overfetch). Triple-buffered register prefetch (distance 2).
// e16 in donated d_out rows 4..19/batch (R7-R9 proven); codes in row 0 own
// columns (R9-proven); no barriers, no atomics, no spill (regs ~224 <= 256).

typedef __attribute__((ext_vector_type(8))) _Float16 half8v;  // 8 fp16 = 4 VGPRs
typedef __attribute__((ext_vector_type(16))) float floatx16;  // 32x32 acc
typedef unsigned int uint;
typedef unsigned short ushort;

#define DD 256
#define KK 2048
#define SS 1024
#define NN 32768
#define WIN 524288  // ushorts per batch window of d_out (1 MB)
#define MFMA_F16 __builtin_amdgcn_mfma_f32_32x32x16_f16

union HU { _Float16 f; ushort u; };

__device__ __forceinline__ void split16(float v, ushort& h, ushort& l) {
    HU a, b;
    a.f = (_Float16)v;                       // RNE
    b.f = (_Float16)(v - (float)a.f);
    h = a.u; l = b.u;
}

// donated region: linear ushort j (0..2^20) -> rows 4..19 of batch windows
__device__ __forceinline__ size_t area_us(uint j) {
    return (size_t)(j >> 15) * WIN + 8192u + (j & 32767u);
}

__global__ __launch_bounds__(256) void hn_kernel(const float* __restrict__ emb,
                                                 float* __restrict__ hn) {
    int k = blockIdx.x * 256 + threadIdx.x;
    float a = 0.f;
#pragma unroll 32
    for (int d = 0; d < DD; ++d) { float e = emb[d * KK + k]; a += e * e; }
    hn[k] = 0.5f * a;
}

// Split emb into fragment blocks: block bix=(g*16+s)*2+p holds 512 ushorts,
// element (c,h,i): j = bix*512 + c*16 + h*8 + i; value = plane p of
// split(emb[(s*16+h*8+i)*KK + g*32+c]).  Thread = (code k, s-quad).
__global__ __launch_bounds__(256) void prep_e(const float* __restrict__ emb,
                                              ushort* __restrict__ e16) {
    const uint t = blockIdx.x * 256 + threadIdx.x;   // 8192 threads
    const uint k = t & (KK - 1);
    const uint sq = t >> 11;                          // 0..3 -> s = sq*4..+3
    const uint g = k >> 5, c = k & 31;
#pragma unroll
    for (uint ds = 0; ds < 4; ++ds) {
        const uint s = sq * 4 + ds;
        ushort h[16], l[16];
#pragma unroll
        for (int i = 0; i < 16; ++i) {
            float v = emb[(size_t)(s * 16 + i) * KK + k];
            split16(v, h[i], l[i]);
        }
        const uint jh = ((g * 16 + s) * 2 + 0) * 512 + c * 16;
        const uint jl = ((g * 16 + s) * 2 + 1) * 512 + c * 16;
        uint4 t4;
#pragma unroll
        for (int hh = 0; hh < 2; ++hh) {
            const ushort* src = hh ? h + 8 : h;
            t4.x = (uint)src[0] | ((uint)src[1] << 16);
            t4.y = (uint)src[2] | ((uint)src[3] << 16);
            t4.z = (uint)src[4] | ((uint)src[5] << 16);
            t4.w = (uint)src[6] | ((uint)src[7] << 16);
            *reinterpret_cast<uint4*>(&e16[area_us(jh + hh * 8)]) = t4;
            const ushort* srl = hh ? l + 8 : l;
            t4.x = (uint)srl[0] | ((uint)srl[1] << 16);
            t4.y = (uint)srl[2] | ((uint)srl[3] << 16);
            t4.z = (uint)srl[4] | ((uint)srl[5] << 16);
            t4.w = (uint)srl[6] | ((uint)srl[7] << 16);
            *reinterpret_cast<uint4*>(&e16[area_us(jl + hh * 8)]) = t4;
        }
    }
}

__global__ __launch_bounds__(256, 2) void vq_fused(
        const float* __restrict__ x, const ushort* __restrict__ e16,
        const float* __restrict__ hn, float* __restrict__ out) {
    // A panel: [plane][lat][256 d], 16-B chunks XOR-swizzled by (lat&7): 64 KB
    __shared__ __align__(16) ushort Ap[2 * 64 * 256];
    __shared__ float sv[4][64];
    __shared__ int   sc[4][64];

    const int tid = threadIdx.x;
    const int lane = tid & 63;
    const int wid = tid >> 6;            // 4 waves, 512 codes each
    const int colk = lane & 31;
    const int half = lane >> 5;
    const int l7 = colk & 7;

    const int blk = blockIdx.x;          // 512 blocks x 64 latents
    const int bq = blk >> 4;             // batch
    const int sb = (blk & 15) * 64;      // spatial base

    // ---- stage A panel once (R9-validated) ----
    {
        const int lat = tid & 63;
        const int jc0 = tid >> 6;
        const int w7 = lat & 7;
        const float* xp = x + (size_t)bq * DD * SS + sb + lat;
        ushort* aH = Ap + lat * 256;
        ushort* aL = Ap + 64 * 256 + lat * 256;
#pragma unroll
        for (int r = 0; r < 8; ++r) {
            const int jc = jc0 + r * 4;
            ushort h[8], l[8];
#pragma unroll
            for (int i = 0; i < 8; ++i) {
                float v = xp[(size_t)(jc * 8 + i) * SS];
                split16(v, h[i], l[i]);
            }
            const int sw = (jc ^ w7) * 8;
            uint4 t;
            t.x = (uint)h[0] | ((uint)h[1] << 16);
            t.y = (uint)h[2] | ((uint)h[3] << 16);
            t.z = (uint)h[4] | ((uint)h[5] << 16);
            t.w = (uint)h[6] | ((uint)h[7] << 16);
            *reinterpret_cast<uint4*>(&aH[sw]) = t;
            t.x = (uint)l[0] | ((uint)l[1] << 16);
            t.y = (uint)l[2] | ((uint)l[3] << 16);
            t.z = (uint)l[4] | ((uint)l[5] << 16);
            t.w = (uint)l[6] | ((uint)l[7] << 16);
            *reinterpret_cast<uint4*>(&aL[sw]) = t;
        }
    }
    __syncthreads();   // the only barrier before the reduction

    const int aB0 = colk * 256;
    const int aB1 = (32 + colk) * 256;
    const uint coff = colk * 16 + half * 8;   // B lane offset within 1-KB block

    float bestv[2][16];
    int bestc[2][16];
#pragma unroll
    for (int t = 0; t < 2; ++t)
#pragma unroll
        for (int r = 0; r < 16; ++r) { bestv[t][r] = 3.4e38f; bestc[t][r] = 0; }

    const uint wbase = wid * 512;

#pragma unroll 1
    for (int nt = 0; nt < 8; ++nt) {
        const uint cb = wbase + nt * 64;
        const uint g0 = cb >> 5;                  // even
        // g0's blocks start at j = g0*16384 -> window g0>>1, inner 0;
        // g1 = g0+1 -> same window, inner +16384. Per k-step: +1024 ushorts.
        const ushort* pg0 = e16 + (size_t)(g0 >> 1) * WIN + 8192u + coff;
        const ushort* pg1 = pg0 + 16384;

        floatx16 acc[2][2];
#pragma unroll
        for (int i = 0; i < 2; ++i)
#pragma unroll
            for (int j = 0; j < 2; ++j) acc[i][j] = (floatx16)(0.0f);

        half8v b0h[3], b0l[3], b1h[3], b1l[3];
        // prefetch ks=0,1 (distance-2 pipeline)
#pragma unroll
        for (int pf = 0; pf < 2; ++pf) {
            b0h[pf] = *reinterpret_cast<const half8v*>(pg0 + pf * 1024);
            b0l[pf] = *reinterpret_cast<const half8v*>(pg0 + pf * 1024 + 512);
            b1h[pf] = *reinterpret_cast<const half8v*>(pg1 + pf * 1024);
            b1l[pf] = *reinterpret_cast<const half8v*>(pg1 + pf * 1024 + 512);
        }

#pragma unroll
        for (int ks = 0; ks < 16; ++ks) {
            const int cur = ks % 3;
            if (ks < 14) {
                const int nx = (ks + 2) % 3;
                b0h[nx] = *reinterpret_cast<const half8v*>(pg0 + (ks + 2) * 1024);
                b0l[nx] = *reinterpret_cast<const half8v*>(pg0 + (ks + 2) * 1024 + 512);
                b1h[nx] = *reinterpret_cast<const half8v*>(pg1 + (ks + 2) * 1024);
                b1l[nx] = *reinterpret_cast<const half8v*>(pg1 + (ks + 2) * 1024 + 512);
            }
            const int sw = ((2 * ks + half) ^ l7) * 8;
            half8v ah0 = *reinterpret_cast<const half8v*>(&Ap[aB0 + sw]);
            half8v ah1 = *reinterpret_cast<const half8v*>(&Ap[aB1 + sw]);
            half8v al0 = *reinterpret_cast<const half8v*>(&Ap[16384 + aB0 + sw]);
            half8v al1 = *reinterpret_cast<const half8v*>(&Ap[16384 + aB1 + sw]);

            acc[0][0] = MFMA_F16(ah0, b0h[cur], acc[0][0], 0, 0, 0);
            acc[0][0] = MFMA_F16(ah0, b0l[cur], acc[0][0], 0, 0, 0);
            acc[0][0] = MFMA_F16(al0, b0h[cur], acc[0][0], 0, 0, 0);

            acc[0][1] = MFMA_F16(ah0, b1h[cur], acc[0][1], 0, 0, 0);
            acc[0][1] = MFMA_F16(ah0, b1l[cur], acc[0][1], 0, 0, 0);
            acc[0][1] = MFMA_F16(al0, b1h[cur], acc[0][1], 0, 0, 0);

            acc[1][0] = MFMA_F16(ah1, b0h[cur], acc[1][0], 0, 0, 0);
            acc[1][0] = MFMA_F16(ah1, b0l[cur], acc[1][0], 0, 0, 0);
            acc[1][0] = MFMA_F16(al1, b0h[cur], acc[1][0], 0, 0, 0);

            acc[1][1] = MFMA_F16(ah1, b1h[cur], acc[1][1], 0, 0, 0);
            acc[1][1] = MFMA_F16(ah1, b1l[cur], acc[1][1], 0, 0, 0);
            acc[1][1] = MFMA_F16(al1, b1h[cur], acc[1][1], 0, 0, 0);
        }

        // ---- n-tile epilogue: scores -> running per-lane argmin ----
        const uint c0 = cb + colk;
        const uint c1 = c0 + 32;
        const float h0 = hn[c0];
        const float h1 = hn[c1];
#pragma unroll
        for (int tm = 0; tm < 2; ++tm) {
#pragma unroll
            for (int r = 0; r < 16; ++r) {
                float s0 = h0 - acc[tm][0][r];
                float s1 = h1 - acc[tm][1][r];
                float v = s0; int cd = (int)c0;
                if (s1 < s0) { v = s1; cd = (int)c1; }   // strict <: smaller code wins
                if (v < bestv[tm][r]) { bestv[tm][r] = v; bestc[tm][r] = cd; }
            }
        }
    }

    // ---- cross-lane argmin over the 32 colk lanes (R9-validated) ----
#pragma unroll
    for (int tm = 0; tm < 2; ++tm) {
#pragma unroll
        for (int r = 0; r < 16; ++r) {
            float v = bestv[tm][r];
            int cd = bestc[tm][r];
#pragma unroll
            for (int mk = 1; mk < 32; mk <<= 1) {
                float ov = __shfl_xor(v, mk);
                int oc = __shfl_xor(cd, mk);
                if (ov < v || (ov == v && oc < cd)) { v = ov; cd = oc; }
            }
            if (colk == 0) {
                const int row = (r & 3) + 8 * (r >> 2) + 4 * half;  // verified C/D map
                sv[wid][tm * 32 + row] = v;
                sc[wid][tm * 32 + row] = cd;
            }
        }
    }
    __syncthreads();
    if (tid < 64) {
        float v = sv[0][tid]; int cd = sc[0][tid];
#pragma unroll
        for (int g = 1; g < 4; ++g) {
            float ov = sv[g][tid]; int oc = sc[g][tid];
            if (ov < v || (ov == v && oc < cd)) { v = ov; cd = oc; }
        }
        uint* cp = reinterpret_cast<uint*>(out + (size_t)bq * DD * SS);
        cp[sb + tid] = (uint)cd;     // row 0, own columns (race-free, R9-proven)
    }
}

__global__ __launch_bounds__(256) void gather_kernel(
        const float* __restrict__ emb, float* __restrict__ out) {
    __shared__ int bc[128];
    const int tid = threadIdx.x;
    const int base_n = blockIdx.x * 128;
    const int bq = base_n >> 10;
    const int sb = base_n & (SS - 1);
    if (tid < 128) {   // read OWN codes from row 0 before overwriting
        const uint* cp = reinterpret_cast<const uint*>(out + (size_t)bq * DD * SS);
        bc[tid] = (int)cp[sb + tid];
    }
    __syncthreads();
    const int mq = tid & 31;
    const int dg = tid >> 5;
    const int k0 = bc[mq * 4 + 0];
    const int k1 = bc[mq * 4 + 1];
    const int k2 = bc[mq * 4 + 2];
    const int k3 = bc[mq * 4 + 3];
#pragma unroll 4
    for (int dd = 0; dd < 32; ++dd) {
        const int d = dg * 32 + dd;
        const float* er = emb + (size_t)d * KK;
        float4 o = make_float4(er[k0], er[k1], er[k2], er[k3]);
        reinterpret_cast<float4*>(&out[((size_t)bq * DD + d) * SS + sb])[mq] = o;
    }
}

extern "C" void kernel_launch(void* const* d_in, const int* in_sizes, int n_in,
                              void* d_out, int out_size, void* d_ws, size_t ws_size,
                              hipStream_t stream) {
    const float* x = (const float*)d_in[0];     // (32,256,32,32)
    const float* emb = (const float*)d_in[1];   // (256,2048)
    float* out = (float*)d_out;
    float* hn = (float*)d_ws;                   // 8 KB (proven safe)

    hipLaunchKernelGGL(prep_e, dim3(32), dim3(256), 0, stream,
                       emb, (ushort*)d_out);
    hipLaunchKernelGGL(hn_kernel, dim3(KK / 256), dim3(256), 0, stream, emb, hn);
    hipLaunchKernelGGL(vq_fused, dim3(NN / 64), dim3(256), 0, stream,
                       x, (const ushort*)d_out, hn, out);
    hipLaunchKernelGGL(gather_kernel, dim3(NN / 128), dim3(256), 0, stream,
                       emb, out);
}